// Round 18
// baseline (121.000 us; speedup 1.0000x reference)
//
#include <hip/hip_runtime.h>

#define A_COEF (-0.75f)

typedef unsigned int u32;
using f16x8 = __attribute__((ext_vector_type(8))) _Float16;
using f32x16 = __attribute__((ext_vector_type(16))) float;
using f32x2  = __attribute__((ext_vector_type(2))) float;

#define NBINS 4096   /* 64 x 64 spatial bins */
#define HB    128    /* hist/scatter blocks */
#define NBLK  1024   /* main kernel grid */

#define ILV_TOTAL  1392640
#define ILV_Q      348160  /* float4 count */
#define ILV_BLOCKS 1360    /* ceil(348160/256) */
#define FRG_BLOCKS 8       /* 30 frags x 64 lanes = 1920 threads */
#define PREP_BLOCKS (ILV_BLOCKS + FRG_BLOCKS + HB)

__device__ __forceinline__ float cc1(float t) {
    return ((A_COEF + 2.0f) * t - (A_COEF + 3.0f)) * t * t + 1.0f;
}
__device__ __forceinline__ float cc2(float t) {
    return ((A_COEF * t - 5.0f * A_COEF) * t + 8.0f * A_COEF) * t - 4.0f * A_COEF;
}

// pack 2 f32 -> 2 f16 (RTZ) in one u32
__device__ __forceinline__ u32 pkrtz(float a, float b) {
    u32 r;
    asm("v_cvt_pkrtz_f16_f32 %0, %1, %2" : "=v"(r) : "v"(a), "v"(b));
    return r;
}

__device__ __forceinline__ int point_bin(float2 xv) {
    float sy = 1.0f / (1.0f + __expf(-xv.x));
    float sx = 1.0f / (1.0f + __expf(-xv.y));
    int qy = min(63, (int)(sy * 64.0f));
    int qx = min(63, (int)(sx * 64.0f));
    return qy * 64 + qx;
}

// ---------------- fused prep: interleave(float4) | frag_pack (f16) | hist ----------------
// tab layout (floats): L0 [0,16384) L1 [16384,81920) L2 [81920,344064) L3 [344064,1392640)
// frag: A-operand = W^T: element(m,k) = W[k][m]; m = mt*32 + (lane&31),
// k = ks*16 + 8*(elem>>2) + 4*(lane>>5) + (elem&3)   [CDNA4 doubled-K = two K-halves]
// P ids (0..29): L0: P=mt (ks=0). L1..L3: 2+8*(L-1)+mt*4+ks. wout: 26+ks.
__global__ __launch_bounds__(256)
void prep_kernel(const float* __restrict__ d0, const float* __restrict__ d1,
                 const float* __restrict__ d2, const float* __restrict__ d3,
                 const float* __restrict__ w0, const float* __restrict__ w1,
                 const float* __restrict__ w2, const float* __restrict__ w3,
                 const float* __restrict__ wout,
                 const float* __restrict__ x, int N, int chunk,
                 float* __restrict__ tab, unsigned short* __restrict__ fr,
                 u32* __restrict__ hist_local) {
    __shared__ u32 lh[NBINS];
    int blk = blockIdx.x;

    if (blk < ILV_BLOCKS) {
        int q = blk * 256 + threadIdx.x;
        if (q >= ILV_Q) return;
        int i = q * 4;   // regions are multiples of 4: no straddle
        const float* in; int base, RR;
        if (i < 81920) {
            if (i < 16384) { in = d0; base = 0;      RR = 4096;  }
            else           { in = d1; base = 16384;  RR = 16384; }
        } else {
            if (i < 344064){ in = d2; base = 81920;  RR = 65536; }
            else           { in = d3; base = 344064; RR = 262144;}
        }
        int t = (i - base) >> 2;
        float4 v;
        v.x = in[0 * RR + t];
        v.y = in[1 * RR + t];
        v.z = in[2 * RR + t];
        v.w = in[3 * RR + t];
        ((float4*)tab)[q] = v;
        return;
    }

    if (blk < ILV_BLOCKS + FRG_BLOCKS) {
        int t = (blk - ILV_BLOCKS) * 256 + threadIdx.x;
        if (t >= 30 * 64) return;
        int P = t >> 6, lane = t & 63;
        int layer, mt, ks;
        if (P < 2)       { layer = 0; mt = P; ks = 0; }
        else if (P < 26) { int r = P - 2; layer = 1 + r / 8; mt = (r & 7) >> 2; ks = r & 3; }
        else             { layer = 4; mt = 0; ks = P - 26; }

        const float* W; int Mdim, Kdim;
        if (layer == 0)      { W = w0;   Mdim = 64; Kdim = 16; }
        else if (layer == 1) { W = w1;   Mdim = 64; Kdim = 64; }
        else if (layer == 2) { W = w2;   Mdim = 64; Kdim = 64; }
        else if (layer == 3) { W = w3;   Mdim = 64; Kdim = 64; }
        else                 { W = wout; Mdim = 4;  Kdim = 64; }

        int m = mt * 32 + (lane & 31);
        int g = lane >> 5;
        unsigned short o[8];
#pragma unroll
        for (int jj = 0; jj < 8; ++jj) {
            int k = ks * 16 + 8 * (jj >> 2) + 4 * g + (jj & 3);
            float v = (m < Mdim && k < Kdim) ? W[k * Mdim + m] : 0.0f;
            _Float16 h = (_Float16)v;   // RNE
            o[jj] = *(unsigned short*)&h;
        }
        u32 a = (u32)o[0] | ((u32)o[1] << 16);
        u32 b = (u32)o[2] | ((u32)o[3] << 16);
        u32 c = (u32)o[4] | ((u32)o[5] << 16);
        u32 d = (u32)o[6] | ((u32)o[7] << 16);
        uint4 val; val.x = a; val.y = b; val.z = c; val.w = d;
        *(uint4*)(fr + (size_t)P * 512 + lane * 8) = val;
        return;
    }

    // hist part
    int b = blk - ILV_BLOCKS - FRG_BLOCKS;   // 0..HB-1
    for (int i = threadIdx.x; i < NBINS; i += 256) lh[i] = 0u;
    __syncthreads();
    int start = b * chunk;
    int end = min(start + chunk, N);
    for (int p = start + threadIdx.x; p < end; p += 256) {
        float2 xv = ((const float2*)x)[p];
        atomicAdd(&lh[point_bin(xv)], 1u);
    }
    __syncthreads();
    for (int i = threadIdx.x; i < NBINS; i += 256)
        hist_local[(size_t)b * NBINS + i] = lh[i];
}

// ---------------- scanA: per-bin cross-block exclusive prefix (in place) + totals ----------------
__global__ __launch_bounds__(256)
void scanA_kernel(u32* __restrict__ hist_local, u32* __restrict__ tot) {
    int bin = blockIdx.x * 256 + threadIdx.x;   // 16 blocks x 256 = 4096
    u32 run = 0;
#pragma unroll 8
    for (int b = 0; b < HB; ++b) {
        u32 v = hist_local[(size_t)b * NBINS + bin];
        hist_local[(size_t)b * NBINS + bin] = run;
        run += v;
    }
    tot[bin] = run;
}

// ---------------- scatter: computes base-scan of tot in-block, then scatters ----------------
__global__ __launch_bounds__(256)
void scatter_kernel(const float* __restrict__ x, int N, int chunk,
                    const u32* __restrict__ hist_local, const u32* __restrict__ tot,
                    u32* __restrict__ pidx, float2* __restrict__ sxy) {
    __shared__ u32 off[NBINS];
    __shared__ u32 part[256];
    int b = blockIdx.x;
    int tI = threadIdx.x;

    // local serial scan of 16 consecutive bins
    u32 loc[16];
    {
        u32 run = 0;
#pragma unroll
        for (int j = 0; j < 16; ++j) {
            u32 v = tot[tI * 16 + j];
            loc[j] = run;
            run += v;
        }
        part[tI] = run;
    }
    __syncthreads();
    // block-wide Hillis-Steele over 256 partials
    for (int o2 = 1; o2 < 256; o2 <<= 1) {
        u32 v = (tI >= o2) ? part[tI - o2] : 0u;
        __syncthreads();
        part[tI] += v;
        __syncthreads();
    }
    u32 excl = (tI > 0) ? part[tI - 1] : 0u;
#pragma unroll
    for (int j = 0; j < 16; ++j) {
        int bin = tI * 16 + j;
        off[bin] = excl + loc[j] + hist_local[(size_t)b * NBINS + bin];
    }
    __syncthreads();

    int start = b * chunk;
    int end = min(start + chunk, N);
    for (int p = start + tI; p < end; p += 256) {
        float2 xv = ((const float2*)x)[p];
        int bin = point_bin(xv);
        u32 pos = atomicAdd(&off[bin], 1u);
        float sy = 1.0f / (1.0f + expf(-xv.x));
        float sx = 1.0f / (1.0f + expf(-xv.y));
        pidx[pos] = (u32)p;
        sxy[pos] = make_float2(sy, sx);
    }
}

// ---------------- sampling (packed-f32 channel math, v_pk_fma_f32) ----------------
__device__ __forceinline__ float4 sample_lvl(const float4* __restrict__ tb, int R, float sy, float sx) {
    float RM1f = (float)(R - 1);
    float fy = sy * RM1f, fx = sx * RM1f;
    float y0f = floorf(fy), x0f = floorf(fx);
    float ty = fy - y0f, tx = fx - x0f;
    int y0 = (int)y0f, x0 = (int)x0f;
    float wxa[4] = {cc2(tx + 1.0f), cc1(tx), cc1(1.0f - tx), cc2(2.0f - tx)};
    float wya[4] = {cc2(ty + 1.0f), cc1(ty), cc1(1.0f - ty), cc2(2.0f - ty)};
    int xs[4], ys[4];
#pragma unroll
    for (int j = 0; j < 4; ++j) {
        xs[j] = min(max(x0 - 1 + j, 0), R - 1);
        ys[j] = min(max(y0 - 1 + j, 0), R - 1);
    }
    f32x2 a01 = {0.f, 0.f}, a23 = {0.f, 0.f};
#pragma unroll
    for (int i = 0; i < 4; ++i) {
        const float4* rp = tb + (size_t)ys[i] * R;
        f32x2 r01 = {0.f, 0.f}, r23 = {0.f, 0.f};
#pragma unroll
        for (int j = 0; j < 4; ++j) {
            float4 v = rp[xs[j]];
            f32x2 w = {wxa[j], wxa[j]};
            f32x2 v01 = {v.x, v.y};
            f32x2 v23 = {v.z, v.w};
            r01 = __builtin_elementwise_fma(w, v01, r01);
            r23 = __builtin_elementwise_fma(w, v23, r23);
        }
        f32x2 wy = {wya[i], wya[i]};
        a01 = __builtin_elementwise_fma(wy, r01, a01);
        a23 = __builtin_elementwise_fma(wy, r23, a23);
    }
    return make_float4(a01.x, a01.y, a23.x, a23.y);
}

// ---------------- MFMA helpers ----------------
__device__ __forceinline__ f16x8 pack8(const u32 b[4]) {
    union { u32 u[4]; f16x8 v; } t;
    t.u[0] = b[0]; t.u[1] = b[1]; t.u[2] = b[2]; t.u[3] = b[3];
    return t.v;
}

// single-f16 MFMA per (mt, ks); setprio(1) around the MFMA cluster (T5)
template <int NKS>
__device__ __forceinline__ void mlp_layer(const unsigned short* __restrict__ fl, int pbase, int lane,
                                          const u32 (&B)[4][4],
                                          const float* __restrict__ bias64, f32x16* __restrict__ acc) {
    int g = lane >> 5;
#pragma unroll
    for (int mt = 0; mt < 2; ++mt) {
        f32x16 a;
        const float* bb = bias64 + 4 * g + 32 * mt;
#pragma unroll
        for (int q = 0; q < 4; ++q) {
            float4 b4 = *(const float4*)(bb + 8 * q);
            a[4 * q + 0] = b4.x; a[4 * q + 1] = b4.y; a[4 * q + 2] = b4.z; a[4 * q + 3] = b4.w;
        }
        __builtin_amdgcn_s_setprio(1);
#pragma unroll
        for (int ks = 0; ks < NKS; ++ks) {
            const f16x8 av = *(const f16x8*)(fl + ((size_t)(pbase + mt * NKS + ks)) * 512 + lane * 8);
            a = __builtin_amdgcn_mfma_f32_32x32x16_f16(av, pack8(B[ks]), a, 0, 0, 0);
        }
        __builtin_amdgcn_s_setprio(0);
        acc[mt] = a;
    }
}

// acc -> relu -> f16 (RTZ pack) -> next layer's B-frags (fully lane-local).
__device__ __forceinline__ void acc_to_B(const f32x16* __restrict__ acc, u32 (&B)[4][4]) {
#pragma unroll
    for (int ks = 0; ks < 4; ++ks) {
#pragma unroll
        for (int w = 0; w < 4; ++w) {
            const int r0 = 8 * (ks & 1) + 4 * (w >> 1) + 2 * (w & 1);
            float va = fmaxf(acc[ks >> 1][r0], 0.f);
            float vb = fmaxf(acc[ks >> 1][r0 + 1], 0.f);
            B[ks][w] = pkrtz(va, vb);
        }
    }
}

// ---------------- main fused kernel (r17 structure, packed-f32 sampling) ----------------
// LDS = 30 f16 frags + biases = 31744 B -> 4 blocks/CU (32 waves/CU cap).
// MODE 0: sorted (sy,sx) from sxy + scatter via pidx; MODE 2: identity order from x
template <int MODE>
__global__ __launch_bounds__(512, 4)
void mrv_mfma_kernel(const float* __restrict__ x,
                     const float* __restrict__ tex_f,
                     const unsigned short* __restrict__ frg,
                     const u32* __restrict__ pidx,
                     const float2* __restrict__ sxy,
                     const float* __restrict__ b0, const float* __restrict__ b1,
                     const float* __restrict__ b2, const float* __restrict__ b3,
                     const float* __restrict__ bout,
                     float* __restrict__ out, int N, int nbatch, int nper) {
    __shared__ __attribute__((aligned(16))) unsigned short frag_lds[30 * 512];
    __shared__ __attribute__((aligned(16))) float bias_lds[4 * 64];

    {
        const uint4* src = (const uint4*)frg;   // 30*512 shorts = 1920 uint4
        uint4* dst = (uint4*)frag_lds;
#pragma unroll
        for (int i = 0; i < 4; ++i) {
            int idx = threadIdx.x + i * 512;
            if (idx < 1920) dst[idx] = src[idx];
        }
        if (threadIdx.x < 256) {
            int L = threadIdx.x >> 6, i = threadIdx.x & 63;
            const float* bp = (L == 0) ? b0 : (L == 1) ? b1 : (L == 2) ? b2 : b3;
            bias_lds[threadIdx.x] = bp[i];
        }
    }
    __syncthreads();

    const int lane = threadIdx.x & 63;
    const int wid = threadIdx.x >> 6;   // 0..7
    const int g = lane >> 5;
    const float4 bo = *(const float4*)bout;
    const float4* tex = (const float4*)tex_f;

    for (int it = 0; it < nper; ++it) {
        int batch = blockIdx.x * nper + it;   // consecutive sorted batches per block
        if (batch >= nbatch) break;
        int slot = batch * 256 + wid * 32 + (lane & 31);
        int sc = min(slot, N - 1);

        int p; float sy, sx;
        if constexpr (MODE == 0) {
            float2 s = sxy[sc];
            sy = s.x; sx = s.y;
            p = (int)pidx[sc];
        } else {
            p = sc;
            float2 xv = ((const float2*)x)[p];
            sy = 1.0f / (1.0f + expf(-xv.x));
            sx = 1.0f / (1.0f + expf(-xv.y));
        }

        // half-wave g needs layer-0 k-set {4g..4g+3, 8+4g..8+4g+3} = levels g and g+2
        float f[8];
#pragma unroll
        for (int lv = 0; lv < 2; ++lv) {
            int lvl = g + 2 * lv;
            int off4 = (lvl == 0) ? 0 : (lvl == 1) ? 4096 : (lvl == 2) ? 20480 : 86016;
            int R = 64 << lvl;
            float4 s = sample_lvl(tex + off4, R, sy, sx);
            f[4 * lv + 0] = s.x; f[4 * lv + 1] = s.y; f[4 * lv + 2] = s.z; f[4 * lv + 3] = s.w;
        }

        u32 B[4][4];
#pragma unroll
        for (int w = 0; w < 4; ++w) B[0][w] = pkrtz(f[2 * w], f[2 * w + 1]);

        f32x16 acc[2];
        mlp_layer<1>(frag_lds, 0,  lane, B, bias_lds + 0,   acc);
        acc_to_B(acc, B);
        mlp_layer<4>(frag_lds, 2,  lane, B, bias_lds + 64,  acc);
        acc_to_B(acc, B);
        mlp_layer<4>(frag_lds, 10, lane, B, bias_lds + 128, acc);
        acc_to_B(acc, B);
        mlp_layer<4>(frag_lds, 18, lane, B, bias_lds + 192, acc);
        acc_to_B(acc, B);

        // output layer: M=4 (padded to 32), single m-tile, P=26..29
        f32x16 ao;
#pragma unroll
        for (int r = 0; r < 16; ++r)
            ao[r] = (g == 0 && r < 4) ? ((r == 0) ? bo.x : (r == 1) ? bo.y : (r == 2) ? bo.z : bo.w) : 0.0f;
        __builtin_amdgcn_s_setprio(1);
#pragma unroll
        for (int ks = 0; ks < 4; ++ks) {
            const f16x8 av = *(const f16x8*)(frag_lds + ((size_t)(26 + ks)) * 512 + lane * 8);
            ao = __builtin_amdgcn_mfma_f32_32x32x16_f16(av, pack8(B[ks]), ao, 0, 0, 0);
        }
        __builtin_amdgcn_s_setprio(0);
        if (g == 0 && slot < N)
            ((float4*)out)[p] = make_float4(ao[0], ao[1], ao[2], ao[3]);
    }
}

// ---------------- fallback (direct-layout f32 VALU) ----------------
__global__ __launch_bounds__(256)
void mrv_fallback_kernel(const float* __restrict__ x,
                         const float* __restrict__ d0, const float* __restrict__ d1,
                         const float* __restrict__ d2, const float* __restrict__ d3,
                         const float* __restrict__ w0, const float* __restrict__ b0,
                         const float* __restrict__ w1, const float* __restrict__ b1,
                         const float* __restrict__ w2, const float* __restrict__ b2,
                         const float* __restrict__ w3, const float* __restrict__ b3,
                         const float* __restrict__ wout, const float* __restrict__ bout,
                         float* __restrict__ out, int n_pts) {
    int n = blockIdx.x * blockDim.x + threadIdx.x;
    if (n >= n_pts) return;
    const float2 xv = *reinterpret_cast<const float2*>(x + (size_t)2 * n);
    float sy = 1.0f / (1.0f + expf(-xv.x));
    float sx = 1.0f / (1.0f + expf(-xv.y));
    float feats[16];
    const float* ds[4] = {d0, d1, d2, d3};
#pragma unroll
    for (int l = 0; l < 4; ++l) {
        int R = 64 << l;
        float RM1f = (float)(R - 1);
        float fy = sy * RM1f, fx = sx * RM1f;
        float y0f = floorf(fy), x0f = floorf(fx);
        float ty = fy - y0f, tx = fx - x0f;
        int y0 = (int)y0f, x0 = (int)x0f;
        float wxa[4] = {cc2(tx + 1.0f), cc1(tx), cc1(1.0f - tx), cc2(2.0f - tx)};
        float wya[4] = {cc2(ty + 1.0f), cc1(ty), cc1(1.0f - ty), cc2(2.0f - ty)};
        int xs[4], ys[4];
#pragma unroll
        for (int j = 0; j < 4; ++j) {
            xs[j] = min(max(x0 - 1 + j, 0), R - 1);
            ys[j] = min(max(y0 - 1 + j, 0), R - 1);
        }
#pragma unroll
        for (int c = 0; c < 4; ++c) {
            const float* cp = ds[l] + (size_t)c * R * R;
            float ac = 0.f;
#pragma unroll
            for (int i = 0; i < 4; ++i) {
                const float* rowp = cp + (size_t)(ys[i] * R);
                float r = 0.f;
#pragma unroll
                for (int j = 0; j < 4; ++j) r = fmaf(wxa[j], rowp[xs[j]], r);
                ac = fmaf(wya[i], r, ac);
            }
            feats[l * 4 + c] = ac;
        }
    }
    float ha[64], hb[64];
#pragma unroll
    for (int j = 0; j < 64; ++j) ha[j] = b0[j];
#pragma unroll
    for (int k = 0; k < 16; ++k) {
        float fk = feats[k];
#pragma unroll
        for (int j = 0; j < 64; ++j) ha[j] = fmaf(fk, w0[k * 64 + j], ha[j]);
    }
#pragma unroll
    for (int j = 0; j < 64; ++j) ha[j] = fmaxf(ha[j], 0.f);
#define LYR(IN, OUT, W, B)                                                  \
    _Pragma("unroll") for (int j = 0; j < 64; ++j) OUT[j] = (B)[j];         \
    _Pragma("unroll") for (int k = 0; k < 64; ++k) {                        \
        float fk = IN[k];                                                   \
        _Pragma("unroll") for (int j = 0; j < 64; ++j)                      \
            OUT[j] = fmaf(fk, (W)[k * 64 + j], OUT[j]);                     \
    }                                                                       \
    _Pragma("unroll") for (int j = 0; j < 64; ++j) OUT[j] = fmaxf(OUT[j], 0.f);
    LYR(ha, hb, w1, b1)
    LYR(hb, ha, w2, b2)
    LYR(ha, hb, w3, b3)
    float o0 = bout[0], o1 = bout[1], o2 = bout[2], o3 = bout[3];
#pragma unroll
    for (int k = 0; k < 64; ++k) {
        float fk = hb[k];
        o0 = fmaf(fk, wout[k * 4 + 0], o0);
        o1 = fmaf(fk, wout[k * 4 + 1], o1);
        o2 = fmaf(fk, wout[k * 4 + 2], o2);
        o3 = fmaf(fk, wout[k * 4 + 3], o3);
    }
    *reinterpret_cast<float4*>(out + (size_t)n * 4) = make_float4(o0, o1, o2, o3);
}

extern "C" void kernel_launch(void* const* d_in, const int* in_sizes, int n_in,
                              void* d_out, int out_size, void* d_ws, size_t ws_size,
                              hipStream_t stream) {
    const float* x  = (const float*)d_in[0];
    const float* d0 = (const float*)d_in[1];
    const float* d1 = (const float*)d_in[2];
    const float* d2 = (const float*)d_in[3];
    const float* d3 = (const float*)d_in[4];
    const float* w0 = (const float*)d_in[5];
    const float* b0 = (const float*)d_in[6];
    const float* w1 = (const float*)d_in[7];
    const float* b1 = (const float*)d_in[8];
    const float* w2 = (const float*)d_in[9];
    const float* b2 = (const float*)d_in[10];
    const float* w3 = (const float*)d_in[11];
    const float* b3 = (const float*)d_in[12];
    const float* wout = (const float*)d_in[13];
    const float* bout = (const float*)d_in[14];
    float* out = (float*)d_out;

    const int N = in_sizes[0] / 2;

    // ws layout: tab | frg | hist_local | tot | reserved | sxy | pidx
    const size_t ftot = ILV_TOTAL;                                 // floats
    const size_t bytes_tab  = ftot * sizeof(float);                // 5,570,560
    const size_t bytes_frg  = (size_t)60 * 512 * sizeof(unsigned short); // keep layout; 30 used
    const size_t bytes_hist = (size_t)HB * NBINS * sizeof(u32);    // 2,097,152
    const size_t bytes_tb   = (size_t)NBINS * sizeof(u32) * 2;     // tot + reserved
    const size_t bytes_sxy  = (size_t)N * sizeof(float2);
    const size_t bytes_pidx = (size_t)N * sizeof(u32);
    const size_t need_mid  = bytes_tab + bytes_frg;
    const size_t need_full = need_mid + bytes_hist + bytes_tb + bytes_sxy + bytes_pidx;

    if (ws_size < need_mid) {
        int blocks = (N + 255) / 256;
        hipLaunchKernelGGL(mrv_fallback_kernel, dim3(blocks), dim3(256), 0, stream,
                           x, d0, d1, d2, d3, w0, b0, w1, b1, w2, b2, w3, b3, wout, bout, out, N);
        return;
    }

    float* ws = (float*)d_ws;
    unsigned short* frg = (unsigned short*)(ws + ftot);
    u32* hist_local = (u32*)((char*)d_ws + need_mid);
    u32* tot  = (u32*)((char*)d_ws + need_mid + bytes_hist);
    float2* sxy = (float2*)((char*)d_ws + need_mid + bytes_hist + bytes_tb);
    u32* pidx = (u32*)((char*)d_ws + need_mid + bytes_hist + bytes_tb + bytes_sxy);

    const int nbatch = (N + 255) / 256;
    const int nper = (nbatch + NBLK - 1) / NBLK;
    const int chunk = (N + HB - 1) / HB;

    if (ws_size >= need_full) {
        hipLaunchKernelGGL(prep_kernel, dim3(PREP_BLOCKS), dim3(256), 0, stream,
                           d0, d1, d2, d3, w0, w1, w2, w3, wout, x, N, chunk,
                           ws, frg, hist_local);
        hipLaunchKernelGGL(scanA_kernel, dim3(NBINS / 256), dim3(256), 0, stream, hist_local, tot);
        hipLaunchKernelGGL(scatter_kernel, dim3(HB), dim3(256), 0, stream,
                           x, N, chunk, hist_local, tot, pidx, sxy);
        hipLaunchKernelGGL((mrv_mfma_kernel<0>), dim3(NBLK), dim3(512), 0, stream,
                           x, ws, frg, pidx, sxy, b0, b1, b2, b3, bout, out, N, nbatch, nper);
    } else {
        hipLaunchKernelGGL(prep_kernel, dim3(ILV_BLOCKS + FRG_BLOCKS), dim3(256), 0, stream,
                           d0, d1, d2, d3, w0, w1, w2, w3, wout, x, N, chunk,
                           ws, frg, hist_local);
        hipLaunchKernelGGL((mrv_mfma_kernel<2>), dim3(NBLK), dim3(512), 0, stream,
                           x, ws, frg, (const u32*)nullptr, (const float2*)nullptr,
                           b0, b1, b2, b3, bout, out, N, nbatch, nper);
    }
}

// Round 19
// 119.622 us; speedup vs baseline: 1.0115x; 1.0115x over previous
//
#include <hip/hip_runtime.h>

#define A_COEF (-0.75f)

typedef unsigned int u32;
using f16x8 = __attribute__((ext_vector_type(8))) _Float16;
using f32x16 = __attribute__((ext_vector_type(16))) float;

#define NBINS 4096   /* 64 x 64 spatial bins */
#define HB    128    /* hist/scatter blocks */
#define NBLK  1024   /* main kernel grid */

#define ILV_TOTAL  1392640
#define ILV_Q      348160  /* float4 count */
#define ILV_BLOCKS 1360    /* ceil(348160/256) */
#define FRG_BLOCKS 8       /* 30 frags x 64 lanes = 1920 threads */
#define PREP_BLOCKS (ILV_BLOCKS + FRG_BLOCKS + HB)

__device__ __forceinline__ float cc1(float t) {
    return ((A_COEF + 2.0f) * t - (A_COEF + 3.0f)) * t * t + 1.0f;
}
__device__ __forceinline__ float cc2(float t) {
    return ((A_COEF * t - 5.0f * A_COEF) * t + 8.0f * A_COEF) * t - 4.0f * A_COEF;
}

// pack 2 f32 -> 2 f16 (RTZ) in one u32
__device__ __forceinline__ u32 pkrtz(float a, float b) {
    u32 r;
    asm("v_cvt_pkrtz_f16_f32 %0, %1, %2" : "=v"(r) : "v"(a), "v"(b));
    return r;
}

__device__ __forceinline__ int point_bin(float2 xv) {
    float sy = 1.0f / (1.0f + __expf(-xv.x));
    float sx = 1.0f / (1.0f + __expf(-xv.y));
    int qy = min(63, (int)(sy * 64.0f));
    int qx = min(63, (int)(sx * 64.0f));
    return qy * 64 + qx;
}

// ---------------- fused prep: interleave(float4) | frag_pack (f16) | hist ----------------
// tab layout (floats): L0 [0,16384) L1 [16384,81920) L2 [81920,344064) L3 [344064,1392640)
// frag: A-operand = W^T: element(m,k) = W[k][m]; m = mt*32 + (lane&31),
// k = ks*16 + 8*(elem>>2) + 4*(lane>>5) + (elem&3)   [CDNA4 doubled-K = two K-halves]
// P ids (0..29): L0: P=mt (ks=0). L1..L3: 2+8*(L-1)+mt*4+ks. wout: 26+ks.
__global__ __launch_bounds__(256)
void prep_kernel(const float* __restrict__ d0, const float* __restrict__ d1,
                 const float* __restrict__ d2, const float* __restrict__ d3,
                 const float* __restrict__ w0, const float* __restrict__ w1,
                 const float* __restrict__ w2, const float* __restrict__ w3,
                 const float* __restrict__ wout,
                 const float* __restrict__ x, int N, int chunk,
                 float* __restrict__ tab, unsigned short* __restrict__ fr,
                 u32* __restrict__ hist_local) {
    __shared__ u32 lh[NBINS];
    int blk = blockIdx.x;

    if (blk < ILV_BLOCKS) {
        int q = blk * 256 + threadIdx.x;
        if (q >= ILV_Q) return;
        int i = q * 4;   // regions are multiples of 4: no straddle
        const float* in; int base, RR;
        if (i < 81920) {
            if (i < 16384) { in = d0; base = 0;      RR = 4096;  }
            else           { in = d1; base = 16384;  RR = 16384; }
        } else {
            if (i < 344064){ in = d2; base = 81920;  RR = 65536; }
            else           { in = d3; base = 344064; RR = 262144;}
        }
        int t = (i - base) >> 2;
        float4 v;
        v.x = in[0 * RR + t];
        v.y = in[1 * RR + t];
        v.z = in[2 * RR + t];
        v.w = in[3 * RR + t];
        ((float4*)tab)[q] = v;
        return;
    }

    if (blk < ILV_BLOCKS + FRG_BLOCKS) {
        int t = (blk - ILV_BLOCKS) * 256 + threadIdx.x;
        if (t >= 30 * 64) return;
        int P = t >> 6, lane = t & 63;
        int layer, mt, ks;
        if (P < 2)       { layer = 0; mt = P; ks = 0; }
        else if (P < 26) { int r = P - 2; layer = 1 + r / 8; mt = (r & 7) >> 2; ks = r & 3; }
        else             { layer = 4; mt = 0; ks = P - 26; }

        const float* W; int Mdim, Kdim;
        if (layer == 0)      { W = w0;   Mdim = 64; Kdim = 16; }
        else if (layer == 1) { W = w1;   Mdim = 64; Kdim = 64; }
        else if (layer == 2) { W = w2;   Mdim = 64; Kdim = 64; }
        else if (layer == 3) { W = w3;   Mdim = 64; Kdim = 64; }
        else                 { W = wout; Mdim = 4;  Kdim = 64; }

        int m = mt * 32 + (lane & 31);
        int g = lane >> 5;
        unsigned short o[8];
#pragma unroll
        for (int jj = 0; jj < 8; ++jj) {
            int k = ks * 16 + 8 * (jj >> 2) + 4 * g + (jj & 3);
            float v = (m < Mdim && k < Kdim) ? W[k * Mdim + m] : 0.0f;
            _Float16 h = (_Float16)v;   // RNE
            o[jj] = *(unsigned short*)&h;
        }
        u32 a = (u32)o[0] | ((u32)o[1] << 16);
        u32 b = (u32)o[2] | ((u32)o[3] << 16);
        u32 c = (u32)o[4] | ((u32)o[5] << 16);
        u32 d = (u32)o[6] | ((u32)o[7] << 16);
        uint4 val; val.x = a; val.y = b; val.z = c; val.w = d;
        *(uint4*)(fr + (size_t)P * 512 + lane * 8) = val;
        return;
    }

    // hist part
    int b = blk - ILV_BLOCKS - FRG_BLOCKS;   // 0..HB-1
    for (int i = threadIdx.x; i < NBINS; i += 256) lh[i] = 0u;
    __syncthreads();
    int start = b * chunk;
    int end = min(start + chunk, N);
    for (int p = start + threadIdx.x; p < end; p += 256) {
        float2 xv = ((const float2*)x)[p];
        atomicAdd(&lh[point_bin(xv)], 1u);
    }
    __syncthreads();
    for (int i = threadIdx.x; i < NBINS; i += 256)
        hist_local[(size_t)b * NBINS + i] = lh[i];
}

// ---------------- scanA: per-bin cross-block exclusive prefix (in place) + totals ----------------
__global__ __launch_bounds__(256)
void scanA_kernel(u32* __restrict__ hist_local, u32* __restrict__ tot) {
    int bin = blockIdx.x * 256 + threadIdx.x;   // 16 blocks x 256 = 4096
    u32 run = 0;
#pragma unroll 8
    for (int b = 0; b < HB; ++b) {
        u32 v = hist_local[(size_t)b * NBINS + bin];
        hist_local[(size_t)b * NBINS + bin] = run;
        run += v;
    }
    tot[bin] = run;
}

// ---------------- scatter: computes base-scan of tot in-block, then scatters ----------------
__global__ __launch_bounds__(256)
void scatter_kernel(const float* __restrict__ x, int N, int chunk,
                    const u32* __restrict__ hist_local, const u32* __restrict__ tot,
                    u32* __restrict__ pidx, float2* __restrict__ sxy) {
    __shared__ u32 off[NBINS];
    __shared__ u32 part[256];
    int b = blockIdx.x;
    int tI = threadIdx.x;

    // local serial scan of 16 consecutive bins
    u32 loc[16];
    {
        u32 run = 0;
#pragma unroll
        for (int j = 0; j < 16; ++j) {
            u32 v = tot[tI * 16 + j];
            loc[j] = run;
            run += v;
        }
        part[tI] = run;
    }
    __syncthreads();
    // block-wide Hillis-Steele over 256 partials
    for (int o2 = 1; o2 < 256; o2 <<= 1) {
        u32 v = (tI >= o2) ? part[tI - o2] : 0u;
        __syncthreads();
        part[tI] += v;
        __syncthreads();
    }
    u32 excl = (tI > 0) ? part[tI - 1] : 0u;
#pragma unroll
    for (int j = 0; j < 16; ++j) {
        int bin = tI * 16 + j;
        off[bin] = excl + loc[j] + hist_local[(size_t)b * NBINS + bin];
    }
    __syncthreads();

    int start = b * chunk;
    int end = min(start + chunk, N);
    for (int p = start + tI; p < end; p += 256) {
        float2 xv = ((const float2*)x)[p];
        int bin = point_bin(xv);
        u32 pos = atomicAdd(&off[bin], 1u);
        float sy = 1.0f / (1.0f + expf(-xv.x));
        float sx = 1.0f / (1.0f + expf(-xv.y));
        pidx[pos] = (u32)p;
        sxy[pos] = make_float2(sy, sx);
    }
}

// ---------------- sampling (runtime R, interleaved float4 texels) ----------------
__device__ __forceinline__ float4 sample_lvl(const float4* __restrict__ tb, int R, float sy, float sx) {
    float RM1f = (float)(R - 1);
    float fy = sy * RM1f, fx = sx * RM1f;
    float y0f = floorf(fy), x0f = floorf(fx);
    float ty = fy - y0f, tx = fx - x0f;
    int y0 = (int)y0f, x0 = (int)x0f;
    float wxa[4] = {cc2(tx + 1.0f), cc1(tx), cc1(1.0f - tx), cc2(2.0f - tx)};
    float wya[4] = {cc2(ty + 1.0f), cc1(ty), cc1(1.0f - ty), cc2(2.0f - ty)};
    int xs[4], ys[4];
#pragma unroll
    for (int j = 0; j < 4; ++j) {
        xs[j] = min(max(x0 - 1 + j, 0), R - 1);
        ys[j] = min(max(y0 - 1 + j, 0), R - 1);
    }
    float a0 = 0.f, a1 = 0.f, a2 = 0.f, a3 = 0.f;
#pragma unroll
    for (int i = 0; i < 4; ++i) {
        const float4* rp = tb + (size_t)ys[i] * R;
        float r0 = 0.f, r1 = 0.f, r2 = 0.f, r3 = 0.f;
#pragma unroll
        for (int j = 0; j < 4; ++j) {
            float4 v = rp[xs[j]];
            r0 = fmaf(wxa[j], v.x, r0);
            r1 = fmaf(wxa[j], v.y, r1);
            r2 = fmaf(wxa[j], v.z, r2);
            r3 = fmaf(wxa[j], v.w, r3);
        }
        a0 = fmaf(wya[i], r0, a0);
        a1 = fmaf(wya[i], r1, a1);
        a2 = fmaf(wya[i], r2, a2);
        a3 = fmaf(wya[i], r3, a3);
    }
    return make_float4(a0, a1, a2, a3);
}

// ---------------- MFMA helpers ----------------
__device__ __forceinline__ f16x8 pack8(const u32 b[4]) {
    union { u32 u[4]; f16x8 v; } t;
    t.u[0] = b[0]; t.u[1] = b[1]; t.u[2] = b[2]; t.u[3] = b[3];
    return t.v;
}

// single-f16 MFMA per (mt, ks); setprio(1) around the MFMA cluster (T5)
template <int NKS>
__device__ __forceinline__ void mlp_layer(const unsigned short* __restrict__ fl, int pbase, int lane,
                                          const u32 (&B)[4][4],
                                          const float* __restrict__ bias64, f32x16* __restrict__ acc) {
    int g = lane >> 5;
#pragma unroll
    for (int mt = 0; mt < 2; ++mt) {
        f32x16 a;
        const float* bb = bias64 + 4 * g + 32 * mt;
#pragma unroll
        for (int q = 0; q < 4; ++q) {
            float4 b4 = *(const float4*)(bb + 8 * q);
            a[4 * q + 0] = b4.x; a[4 * q + 1] = b4.y; a[4 * q + 2] = b4.z; a[4 * q + 3] = b4.w;
        }
        __builtin_amdgcn_s_setprio(1);
#pragma unroll
        for (int ks = 0; ks < NKS; ++ks) {
            const f16x8 av = *(const f16x8*)(fl + ((size_t)(pbase + mt * NKS + ks)) * 512 + lane * 8);
            a = __builtin_amdgcn_mfma_f32_32x32x16_f16(av, pack8(B[ks]), a, 0, 0, 0);
        }
        __builtin_amdgcn_s_setprio(0);
        acc[mt] = a;
    }
}

// acc -> relu -> f16 (RTZ pack) -> next layer's B-frags (fully lane-local).
__device__ __forceinline__ void acc_to_B(const f32x16* __restrict__ acc, u32 (&B)[4][4]) {
#pragma unroll
    for (int ks = 0; ks < 4; ++ks) {
#pragma unroll
        for (int w = 0; w < 4; ++w) {
            const int r0 = 8 * (ks & 1) + 4 * (w >> 1) + 2 * (w & 1);
            float va = fmaxf(acc[ks >> 1][r0], 0.f);
            float vb = fmaxf(acc[ks >> 1][r0 + 1], 0.f);
            B[ks][w] = pkrtz(va, vb);
        }
    }
}

// ---------------- main fused kernel (r17-best structure, single-f16 path) ----------------
// LDS = 30 f16 frags + biases = 31744 B. __launch_bounds__(512,4): full 128-VGPR budget.
// MODE 0: sorted (sy,sx) from sxy + scatter via pidx; MODE 2: identity order from x
template <int MODE>
__global__ __launch_bounds__(512, 4)
void mrv_mfma_kernel(const float* __restrict__ x,
                     const float* __restrict__ tex_f,
                     const unsigned short* __restrict__ frg,
                     const u32* __restrict__ pidx,
                     const float2* __restrict__ sxy,
                     const float* __restrict__ b0, const float* __restrict__ b1,
                     const float* __restrict__ b2, const float* __restrict__ b3,
                     const float* __restrict__ bout,
                     float* __restrict__ out, int N, int nbatch, int nper) {
    __shared__ __attribute__((aligned(16))) unsigned short frag_lds[30 * 512];
    __shared__ __attribute__((aligned(16))) float bias_lds[4 * 64];

    {
        const uint4* src = (const uint4*)frg;   // 30*512 shorts = 1920 uint4
        uint4* dst = (uint4*)frag_lds;
#pragma unroll
        for (int i = 0; i < 4; ++i) {
            int idx = threadIdx.x + i * 512;
            if (idx < 1920) dst[idx] = src[idx];
        }
        if (threadIdx.x < 256) {
            int L = threadIdx.x >> 6, i = threadIdx.x & 63;
            const float* bp = (L == 0) ? b0 : (L == 1) ? b1 : (L == 2) ? b2 : b3;
            bias_lds[threadIdx.x] = bp[i];
        }
    }
    __syncthreads();

    const int lane = threadIdx.x & 63;
    const int wid = threadIdx.x >> 6;   // 0..7
    const int g = lane >> 5;
    const float4 bo = *(const float4*)bout;
    const float4* tex = (const float4*)tex_f;

    for (int it = 0; it < nper; ++it) {
        int batch = blockIdx.x * nper + it;   // consecutive sorted batches per block
        if (batch >= nbatch) break;
        int slot = batch * 256 + wid * 32 + (lane & 31);
        int sc = min(slot, N - 1);

        int p; float sy, sx;
        if constexpr (MODE == 0) {
            float2 s = sxy[sc];
            sy = s.x; sx = s.y;
            p = (int)pidx[sc];
        } else {
            p = sc;
            float2 xv = ((const float2*)x)[p];
            sy = 1.0f / (1.0f + expf(-xv.x));
            sx = 1.0f / (1.0f + expf(-xv.y));
        }

        // half-wave g needs layer-0 k-set {4g..4g+3, 8+4g..8+4g+3} = levels g and g+2
        float f[8];
#pragma unroll
        for (int lv = 0; lv < 2; ++lv) {
            int lvl = g + 2 * lv;
            int off4 = (lvl == 0) ? 0 : (lvl == 1) ? 4096 : (lvl == 2) ? 20480 : 86016;
            int R = 64 << lvl;
            float4 s = sample_lvl(tex + off4, R, sy, sx);
            f[4 * lv + 0] = s.x; f[4 * lv + 1] = s.y; f[4 * lv + 2] = s.z; f[4 * lv + 3] = s.w;
        }

        u32 B[4][4];
#pragma unroll
        for (int w = 0; w < 4; ++w) B[0][w] = pkrtz(f[2 * w], f[2 * w + 1]);

        f32x16 acc[2];
        mlp_layer<1>(frag_lds, 0,  lane, B, bias_lds + 0,   acc);
        acc_to_B(acc, B);
        mlp_layer<4>(frag_lds, 2,  lane, B, bias_lds + 64,  acc);
        acc_to_B(acc, B);
        mlp_layer<4>(frag_lds, 10, lane, B, bias_lds + 128, acc);
        acc_to_B(acc, B);
        mlp_layer<4>(frag_lds, 18, lane, B, bias_lds + 192, acc);
        acc_to_B(acc, B);

        // output layer: M=4 (padded to 32), single m-tile, P=26..29
        f32x16 ao;
#pragma unroll
        for (int r = 0; r < 16; ++r)
            ao[r] = (g == 0 && r < 4) ? ((r == 0) ? bo.x : (r == 1) ? bo.y : (r == 2) ? bo.z : bo.w) : 0.0f;
        __builtin_amdgcn_s_setprio(1);
#pragma unroll
        for (int ks = 0; ks < 4; ++ks) {
            const f16x8 av = *(const f16x8*)(frag_lds + ((size_t)(26 + ks)) * 512 + lane * 8);
            ao = __builtin_amdgcn_mfma_f32_32x32x16_f16(av, pack8(B[ks]), ao, 0, 0, 0);
        }
        __builtin_amdgcn_s_setprio(0);
        if (g == 0 && slot < N)
            ((float4*)out)[p] = make_float4(ao[0], ao[1], ao[2], ao[3]);
    }
}

// ---------------- fallback (direct-layout f32 VALU) ----------------
__global__ __launch_bounds__(256)
void mrv_fallback_kernel(const float* __restrict__ x,
                         const float* __restrict__ d0, const float* __restrict__ d1,
                         const float* __restrict__ d2, const float* __restrict__ d3,
                         const float* __restrict__ w0, const float* __restrict__ b0,
                         const float* __restrict__ w1, const float* __restrict__ b1,
                         const float* __restrict__ w2, const float* __restrict__ b2,
                         const float* __restrict__ w3, const float* __restrict__ b3,
                         const float* __restrict__ wout, const float* __restrict__ bout,
                         float* __restrict__ out, int n_pts) {
    int n = blockIdx.x * blockDim.x + threadIdx.x;
    if (n >= n_pts) return;
    const float2 xv = *reinterpret_cast<const float2*>(x + (size_t)2 * n);
    float sy = 1.0f / (1.0f + expf(-xv.x));
    float sx = 1.0f / (1.0f + expf(-xv.y));
    float feats[16];
    const float* ds[4] = {d0, d1, d2, d3};
#pragma unroll
    for (int l = 0; l < 4; ++l) {
        int R = 64 << l;
        float RM1f = (float)(R - 1);
        float fy = sy * RM1f, fx = sx * RM1f;
        float y0f = floorf(fy), x0f = floorf(fx);
        float ty = fy - y0f, tx = fx - x0f;
        int y0 = (int)y0f, x0 = (int)x0f;
        float wxa[4] = {cc2(tx + 1.0f), cc1(tx), cc1(1.0f - tx), cc2(2.0f - tx)};
        float wya[4] = {cc2(ty + 1.0f), cc1(ty), cc1(1.0f - ty), cc2(2.0f - ty)};
        int xs[4], ys[4];
#pragma unroll
        for (int j = 0; j < 4; ++j) {
            xs[j] = min(max(x0 - 1 + j, 0), R - 1);
            ys[j] = min(max(y0 - 1 + j, 0), R - 1);
        }
#pragma unroll
        for (int c = 0; c < 4; ++c) {
            const float* cp = ds[l] + (size_t)c * R * R;
            float ac = 0.f;
#pragma unroll
            for (int i = 0; i < 4; ++i) {
                const float* rowp = cp + (size_t)(ys[i] * R);
                float r = 0.f;
#pragma unroll
                for (int j = 0; j < 4; ++j) r = fmaf(wxa[j], rowp[xs[j]], r);
                ac = fmaf(wya[i], r, ac);
            }
            feats[l * 4 + c] = ac;
        }
    }
    float ha[64], hb[64];
#pragma unroll
    for (int j = 0; j < 64; ++j) ha[j] = b0[j];
#pragma unroll
    for (int k = 0; k < 16; ++k) {
        float fk = feats[k];
#pragma unroll
        for (int j = 0; j < 64; ++j) ha[j] = fmaf(fk, w0[k * 64 + j], ha[j]);
    }
#pragma unroll
    for (int j = 0; j < 64; ++j) ha[j] = fmaxf(ha[j], 0.f);
#define LYR(IN, OUT, W, B)                                                  \
    _Pragma("unroll") for (int j = 0; j < 64; ++j) OUT[j] = (B)[j];         \
    _Pragma("unroll") for (int k = 0; k < 64; ++k) {                        \
        float fk = IN[k];                                                   \
        _Pragma("unroll") for (int j = 0; j < 64; ++j)                      \
            OUT[j] = fmaf(fk, (W)[k * 64 + j], OUT[j]);                     \
    }                                                                       \
    _Pragma("unroll") for (int j = 0; j < 64; ++j) OUT[j] = fmaxf(OUT[j], 0.f);
    LYR(ha, hb, w1, b1)
    LYR(hb, ha, w2, b2)
    LYR(ha, hb, w3, b3)
    float o0 = bout[0], o1 = bout[1], o2 = bout[2], o3 = bout[3];
#pragma unroll
    for (int k = 0; k < 64; ++k) {
        float fk = hb[k];
        o0 = fmaf(fk, wout[k * 4 + 0], o0);
        o1 = fmaf(fk, wout[k * 4 + 1], o1);
        o2 = fmaf(fk, wout[k * 4 + 2], o2);
        o3 = fmaf(fk, wout[k * 4 + 3], o3);
    }
    *reinterpret_cast<float4*>(out + (size_t)n * 4) = make_float4(o0, o1, o2, o3);
}

extern "C" void kernel_launch(void* const* d_in, const int* in_sizes, int n_in,
                              void* d_out, int out_size, void* d_ws, size_t ws_size,
                              hipStream_t stream) {
    const float* x  = (const float*)d_in[0];
    const float* d0 = (const float*)d_in[1];
    const float* d1 = (const float*)d_in[2];
    const float* d2 = (const float*)d_in[3];
    const float* d3 = (const float*)d_in[4];
    const float* w0 = (const float*)d_in[5];
    const float* b0 = (const float*)d_in[6];
    const float* w1 = (const float*)d_in[7];
    const float* b1 = (const float*)d_in[8];
    const float* w2 = (const float*)d_in[9];
    const float* b2 = (const float*)d_in[10];
    const float* w3 = (const float*)d_in[11];
    const float* b3 = (const float*)d_in[12];
    const float* wout = (const float*)d_in[13];
    const float* bout = (const float*)d_in[14];
    float* out = (float*)d_out;

    const int N = in_sizes[0] / 2;

    // ws layout: tab | frg | hist_local | tot | reserved | sxy | pidx
    const size_t ftot = ILV_TOTAL;                                 // floats
    const size_t bytes_tab  = ftot * sizeof(float);                // 5,570,560
    const size_t bytes_frg  = (size_t)60 * 512 * sizeof(unsigned short); // keep layout; 30 used
    const size_t bytes_hist = (size_t)HB * NBINS * sizeof(u32);    // 2,097,152
    const size_t bytes_tb   = (size_t)NBINS * sizeof(u32) * 2;     // tot + reserved
    const size_t bytes_sxy  = (size_t)N * sizeof(float2);
    const size_t bytes_pidx = (size_t)N * sizeof(u32);
    const size_t need_mid  = bytes_tab + bytes_frg;
    const size_t need_full = need_mid + bytes_hist + bytes_tb + bytes_sxy + bytes_pidx;

    if (ws_size < need_mid) {
        int blocks = (N + 255) / 256;
        hipLaunchKernelGGL(mrv_fallback_kernel, dim3(blocks), dim3(256), 0, stream,
                           x, d0, d1, d2, d3, w0, b0, w1, b1, w2, b2, w3, b3, wout, bout, out, N);
        return;
    }

    float* ws = (float*)d_ws;
    unsigned short* frg = (unsigned short*)(ws + ftot);
    u32* hist_local = (u32*)((char*)d_ws + need_mid);
    u32* tot  = (u32*)((char*)d_ws + need_mid + bytes_hist);
    float2* sxy = (float2*)((char*)d_ws + need_mid + bytes_hist + bytes_tb);
    u32* pidx = (u32*)((char*)d_ws + need_mid + bytes_hist + bytes_tb + bytes_sxy);

    const int nbatch = (N + 255) / 256;
    const int nper = (nbatch + NBLK - 1) / NBLK;
    const int chunk = (N + HB - 1) / HB;

    if (ws_size >= need_full) {
        hipLaunchKernelGGL(prep_kernel, dim3(PREP_BLOCKS), dim3(256), 0, stream,
                           d0, d1, d2, d3, w0, w1, w2, w3, wout, x, N, chunk,
                           ws, frg, hist_local);
        hipLaunchKernelGGL(scanA_kernel, dim3(NBINS / 256), dim3(256), 0, stream, hist_local, tot);
        hipLaunchKernelGGL(scatter_kernel, dim3(HB), dim3(256), 0, stream,
                           x, N, chunk, hist_local, tot, pidx, sxy);
        hipLaunchKernelGGL((mrv_mfma_kernel<0>), dim3(NBLK), dim3(512), 0, stream,
                           x, ws, frg, pidx, sxy, b0, b1, b2, b3, bout, out, N, nbatch, nper);
    } else {
        hipLaunchKernelGGL(prep_kernel, dim3(ILV_BLOCKS + FRG_BLOCKS), dim3(256), 0, stream,
                           d0, d1, d2, d3, w0, w1, w2, w3, wout, x, N, chunk,
                           ws, frg, hist_local);
        hipLaunchKernelGGL((mrv_mfma_kernel<2>), dim3(NBLK), dim3(512), 0, stream,
                           x, ws, frg, (const u32*)nullptr, (const float2*)nullptr,
                           b0, b1, b2, b3, bout, out, N, nbatch, nper);
    }
}